// Round 7
// baseline (199.041 us; speedup 1.0000x reference)
//
#include <hip/hip_runtime.h>
#include <math.h>

typedef float vfloat4 __attribute__((ext_vector_type(4)));

// Problem constants
#define BB 8
#define CC 64
#define HH 256
#define WW 256
#define HP 257                     // output spatial (H+1)
#define NPB (HP * HP)              // 66049 outputs per batch

// Padded channel-sum buffer: 262 rows (3 halo top/bottom), stride 268 floats
// (4 left-halo floats for alignment, >=3 halo + vector-load slack on right).
#define SROWS 262
#define SSTR  268
#define SPIMG (SROWS * SSTR)       // 70216 floats per image
#define SSTR4 (SSTR / 4)           // 67

// y buffer: padded row stride 260 (mult of 4) for aligned float4 access
#define YSTR 260
#define YIMG (HP * YSTR)           // 66820

// Workspace layout (floats):
#define OFF_PART 0                 // 8*66*2 = 1056 partial pairs
#define OFF_Y    2048              // 8*66820 = 534560
#define OFF_SPAD 536608            // 8*70216 = 561728 (total ~4.4 MB)

// K1 sizing: 1024 row-pair blocks (8 img x 128 pairs) + 37 pad blocks
#define CHBLKS 1024
#define PAD_PER_IMG 1170           // 6*67 full rows + 256*3 side cols
#define NPAD (BB * PAD_PER_IMG)    // 9360
#define PADBLKS ((NPAD + 255) / 256)   // 37

// K3/K4 sizing: per batch, 257 rows x 65 w-groups of 4
#define GPB (HP * 65)              // 16705 groups per batch
#define CBLK 66                    // ceil(16705/256)

// ---- K1: channel sum, 2 rows/block (4 groups x 16 ch, LDS reduce) ----
__global__ __launch_bounds__(256) void k_chansum(const float* __restrict__ x,
                                                 float* __restrict__ ws) {
    int blk = blockIdx.x;
    int t = threadIdx.x;
    vfloat4* sp4 = reinterpret_cast<vfloat4*>(ws + OFF_SPAD);
    if (blk < CHBLKS) {
        int img = blk >> 7;                 // 128 row-pair blocks per image
        int row = (blk & 127) * 2;          // rows row, row+1
        int p = t & 63;                     // float4 col within row
        int cg = t >> 6;                    // channel group 0..3
        const vfloat4* xpA = reinterpret_cast<const vfloat4*>(x)
                             + (size_t)img * (CC * 16384)
                             + (size_t)(cg * 16) * 16384 + row * 64 + p;
        const vfloat4* xpB = xpA + 64;      // next row
        vfloat4 accA = {0.f, 0.f, 0.f, 0.f};
        vfloat4 accB = {0.f, 0.f, 0.f, 0.f};
#pragma unroll
        for (int c = 0; c < 16; ++c) accA += xpA[(size_t)c * 16384];
#pragma unroll
        for (int c = 0; c < 16; ++c) accB += xpB[(size_t)c * 16384];
        __shared__ vfloat4 ldsA[256];
        __shared__ vfloat4 ldsB[256];
        ldsA[t] = accA;
        ldsB[t] = accB;
        __syncthreads();
        if (t < 64) {
            vfloat4 s = ldsA[t] + ldsA[t + 64] + ldsA[t + 128] + ldsA[t + 192];
            sp4[img * (SPIMG / 4) + (row + 3) * SSTR4 + 1 + t] = s;
        } else if (t < 128) {
            int u = t - 64;
            vfloat4 s = ldsB[u] + ldsB[u + 64] + ldsB[u + 128] + ldsB[u + 192];
            sp4[img * (SPIMG / 4) + (row + 4) * SSTR4 + 1 + u] = s;
        }
    } else {
        int k = (blk - CHBLKS) * 256 + t;
        if (k < NPAD) {
            int img = k / PAD_PER_IMG;
            int k2 = k % PAD_PER_IMG;
            int row, col4;
            if (k2 < 402) {                 // 3 top + 3 bottom full rows
                int rr = k2 / 67;
                row = (rr < 3) ? rr : 256 + rr;   // 0,1,2 / 259,260,261
                col4 = k2 % 67;
            } else {                        // side pads, rows 3..258
                int k3 = k2 - 402;
                row = 3 + k3 / 3;
                int m = k3 % 3;
                col4 = (m == 0) ? 0 : 64 + m;     // 0, 65, 66
            }
            vfloat4 z = {0.f, 0.f, 0.f, 0.f};
            sp4[img * (SPIMG / 4) + row * SSTR4 + col4] = z;
        }
    }
}

// ---- build combined 6x6 weights: (2x2 avg-pool) ∘ (16-tap 5x5 shift stencil) ----
__device__ __forceinline__ void build_w(const float* __restrict__ cw, float W[6][6]) {
    float T[5][5];
#pragma unroll
    for (int i = 0; i < 5; ++i)
#pragma unroll
        for (int j = 0; j < 5; ++j) T[i][j] = 0.f;
#pragma unroll
    for (int d = 0; d < 5; ++d) { T[0][d] = -cw[d]; T[4][d] = cw[4 - d]; }
    T[1][4] = -cw[5]; T[2][4] = -cw[6]; T[3][4] = -cw[7];
    T[1][0] =  cw[7]; T[2][0] =  cw[6]; T[3][0] =  cw[5];
#pragma unroll
    for (int u = 0; u < 6; ++u)
#pragma unroll
        for (int v = 0; v < 6; ++v) {
            float a = 0.f;
#pragma unroll
            for (int dr = u - 1; dr <= u; ++dr)
#pragma unroll
                for (int dc = v - 1; dc <= v; ++dc)
                    if (dr >= 0 && dr < 5 && dc >= 0 && dc < 5) a += T[dr][dc];
            W[u][v] = 0.25f * a;
        }
}

// ---- K3: 6x6 stencil, 4 outputs/thread via float4 row loads; y + partials ----
__global__ __launch_bounds__(256) void k_conv(float* __restrict__ ws,
                                              const float* __restrict__ cw,
                                              const float* __restrict__ cbp) {
    int b = blockIdx.y;
    int g = blockIdx.x * 256 + threadIdx.x;
    float v1 = 0.f, v2 = 0.f;
    if (g < GPB) {
        float W[6][6];
        build_w(cw, W);
        const float cb = cbp[0];
        int h = g / 65, wg = g % 65, w0 = wg * 4;
        const float* sb = ws + OFF_SPAD + b * SPIMG + h * SSTR + w0;
        float acc[4] = {cb, cb, cb, cb};
#pragma unroll
        for (int u = 0; u < 6; ++u) {
            const vfloat4* rp = reinterpret_cast<const vfloat4*>(sb + u * SSTR);
            vfloat4 A = rp[0], Bv = rp[1], Cv = rp[2];
            float r[12] = {A.x, A.y, A.z, A.w, Bv.x, Bv.y, Bv.z, Bv.w,
                           Cv.x, Cv.y, Cv.z, Cv.w};
#pragma unroll
            for (int j = 0; j < 4; ++j)
#pragma unroll
                for (int v = 0; v < 6; ++v)
                    acc[j] += W[u][v] * r[1 + j + v];
        }
        vfloat4 yo = {acc[0], acc[1], acc[2], acc[3]};
        reinterpret_cast<vfloat4*>(ws + OFF_Y + b * YIMG + h * YSTR + w0)[0] = yo;
        int nv = (wg == 64) ? 1 : 4;
#pragma unroll
        for (int j = 0; j < 4; ++j)
            if (j < nv) { v1 += acc[j]; v2 += acc[j] * acc[j]; }
    }
    // block reduce (sum, sumsq)
    for (int off = 32; off > 0; off >>= 1) {
        v1 += __shfl_down(v1, off);
        v2 += __shfl_down(v2, off);
    }
    __shared__ float red[8];
    int lane = threadIdx.x & 63, wid = threadIdx.x >> 6;
    if (lane == 0) { red[wid] = v1; red[4 + wid] = v2; }
    __syncthreads();
    if (threadIdx.x == 0) {
        int pb = b * CBLK + blockIdx.x;
        ws[OFF_PART + 2 * pb]     = red[0] + red[1] + red[2] + red[3];
        ws[OFF_PART + 2 * pb + 1] = red[4] + red[5] + red[6] + red[7];
    }
}

// ---- K4: per-block stats reduce + normalize + leaky-relu ----
__global__ __launch_bounds__(256) void k_final(const float* __restrict__ ws,
                                               float* __restrict__ out) {
    int b = blockIdx.y;
    int tid = threadIdx.x;
    float v1 = 0.f, v2 = 0.f;
    if (tid < CBLK) {
        v1 = ws[OFF_PART + 2 * (b * CBLK + tid)];
        v2 = ws[OFF_PART + 2 * (b * CBLK + tid) + 1];
    }
    for (int off = 32; off > 0; off >>= 1) {
        v1 += __shfl_down(v1, off);
        v2 += __shfl_down(v2, off);
    }
    __shared__ float red[8];
    __shared__ float st[2];
    int lane = tid & 63, wid = tid >> 6;
    if (lane == 0) { red[wid] = v1; red[4 + wid] = v2; }
    __syncthreads();
    if (tid == 0) {
        float s1 = red[0] + red[1] + red[2] + red[3];
        float s2 = red[4] + red[5] + red[6] + red[7];
        float mu = s1 / (float)NPB;
        float var = s2 / (float)NPB - mu * mu;
        st[0] = mu;
        st[1] = 1.0f / sqrtf(var + 1e-5f);
    }
    __syncthreads();
    const float mu = st[0], rs = st[1];
    int g = blockIdx.x * 256 + tid;
    if (g < GPB) {
        int h = g / 65, wg = g % 65, w0 = wg * 4;
        vfloat4 yv = reinterpret_cast<const vfloat4*>(ws + OFF_Y + b * YIMG
                                                      + h * YSTR + w0)[0];
        float yr[4] = {yv.x, yv.y, yv.z, yv.w};
        int nv = (wg == 64) ? 1 : 4;
        float* ob = out + b * NPB + h * HP + w0;
#pragma unroll
        for (int j = 0; j < 4; ++j)
            if (j < nv) {
                float z = (yr[j] - mu) * rs;
                ob[j] = (z >= 0.f) ? z : 0.01f * z;
            }
    }
}

extern "C" void kernel_launch(void* const* d_in, const int* in_sizes, int n_in,
                              void* d_out, int out_size, void* d_ws, size_t ws_size,
                              hipStream_t stream) {
    const float* x  = (const float*)d_in[0];   // [8,64,256,256]
    const float* cw = (const float*)d_in[1];   // [1,8]
    const float* cb = (const float*)d_in[2];   // [1]
    float* out = (float*)d_out;                // [8,1,257,257]
    float* ws  = (float*)d_ws;

    k_chansum<<<CHBLKS + PADBLKS, 256, 0, stream>>>(x, ws);
    dim3 g(CBLK, BB);
    k_conv<<<g, 256, 0, stream>>>(ws, cw, cb);
    k_final<<<g, 256, 0, stream>>>(ws, out);
}

// Round 8
// 190.646 us; speedup vs baseline: 1.0440x; 1.0440x over previous
//
#include <hip/hip_runtime.h>
#include <math.h>

typedef float vfloat4 __attribute__((ext_vector_type(4)));

// Problem constants
#define BB 8
#define CC 64
#define HH 256
#define WW 256
#define HP 257                     // output spatial (H+1)
#define NPB (HP * HP)              // 66049 outputs per batch

// Padded channel-sum buffer: 262 rows (3 halo top/bottom), stride 268 floats
// (4 left-halo floats for alignment, >=3 halo + vector-load slack on right).
#define SROWS 262
#define SSTR  268
#define SPIMG (SROWS * SSTR)       // 70216 floats per image
#define SSTR4 (SSTR / 4)           // 67

// y buffer: padded row stride 260 (mult of 4) for aligned float4 access
#define YSTR 260
#define YIMG (HP * YSTR)           // 66820

// Workspace layout (floats):
#define OFF_PART 0                 // 8*66*2 = 1056 partial pairs
#define OFF_Y    2048              // 8*66820 = 534560
#define OFF_SPAD 536608            // 8*70216 = 561728 (total ~4.4 MB)

// K1 sizing: 2048 row-blocks (8 img x 256 rows) + 37 pad blocks
// NOTE (R7 post-mortem): 1 row/block + 16-deep NT chains is the measured
// optimum; 2 rows/block or dropping the NT hint regressed by ~8 us.
#define CHBLKS 2048
#define PAD_PER_IMG 1170           // 6*67 full rows + 256*3 side cols
#define NPAD (BB * PAD_PER_IMG)    // 9360
#define PADBLKS ((NPAD + 255) / 256)   // 37

// K3/K4 sizing: per batch, 257 rows x 65 w-groups of 4
#define GPB (HP * 65)              // 16705 groups per batch
#define CBLK 66                    // ceil(16705/256)

// ---- K1: channel sum (4 groups x 16 ch, LDS reduce) into padded buffer ----
__global__ __launch_bounds__(256) void k_chansum(const float* __restrict__ x,
                                                 float* __restrict__ ws) {
    int blk = blockIdx.x;
    int t = threadIdx.x;
    vfloat4* sp4 = reinterpret_cast<vfloat4*>(ws + OFF_SPAD);
    if (blk < CHBLKS) {
        int img = blk >> 8;                 // 256 row-blocks per image
        int row = blk & 255;
        int p = t & 63;                     // float4 col within row
        int cg = t >> 6;                    // channel group 0..3
        const vfloat4* xp = reinterpret_cast<const vfloat4*>(x)
                            + (size_t)img * (CC * 16384)
                            + (size_t)(cg * 16) * 16384 + row * 64 + p;
        vfloat4 acc = {0.f, 0.f, 0.f, 0.f};
#pragma unroll
        for (int c = 0; c < 16; ++c)
            acc += __builtin_nontemporal_load(&xp[(size_t)c * 16384]);
        __shared__ vfloat4 lds[256];
        lds[t] = acc;
        __syncthreads();
        if (t < 64) {
            vfloat4 s = lds[t] + lds[t + 64] + lds[t + 128] + lds[t + 192];
            sp4[img * (SPIMG / 4) + (row + 3) * SSTR4 + 1 + t] = s;
        }
    } else {
        int k = (blk - CHBLKS) * 256 + t;
        if (k < NPAD) {
            int img = k / PAD_PER_IMG;
            int k2 = k % PAD_PER_IMG;
            int row, col4;
            if (k2 < 402) {                 // 3 top + 3 bottom full rows
                int rr = k2 / 67;
                row = (rr < 3) ? rr : 256 + rr;   // 0,1,2 / 259,260,261
                col4 = k2 % 67;
            } else {                        // side pads, rows 3..258
                int k3 = k2 - 402;
                row = 3 + k3 / 3;
                int m = k3 % 3;
                col4 = (m == 0) ? 0 : 64 + m;     // 0, 65, 66
            }
            vfloat4 z = {0.f, 0.f, 0.f, 0.f};
            sp4[img * (SPIMG / 4) + row * SSTR4 + col4] = z;
        }
    }
}

// ---- build combined 6x6 weights: (2x2 avg-pool) ∘ (16-tap 5x5 shift stencil) ----
__device__ __forceinline__ void build_w(const float* __restrict__ cw, float W[6][6]) {
    float T[5][5];
#pragma unroll
    for (int i = 0; i < 5; ++i)
#pragma unroll
        for (int j = 0; j < 5; ++j) T[i][j] = 0.f;
#pragma unroll
    for (int d = 0; d < 5; ++d) { T[0][d] = -cw[d]; T[4][d] = cw[4 - d]; }
    T[1][4] = -cw[5]; T[2][4] = -cw[6]; T[3][4] = -cw[7];
    T[1][0] =  cw[7]; T[2][0] =  cw[6]; T[3][0] =  cw[5];
#pragma unroll
    for (int u = 0; u < 6; ++u)
#pragma unroll
        for (int v = 0; v < 6; ++v) {
            float a = 0.f;
#pragma unroll
            for (int dr = u - 1; dr <= u; ++dr)
#pragma unroll
                for (int dc = v - 1; dc <= v; ++dc)
                    if (dr >= 0 && dr < 5 && dc >= 0 && dc < 5) a += T[dr][dc];
            W[u][v] = 0.25f * a;
        }
}

// ---- K3: 6x6 stencil, 4 outputs/thread via float4 row loads; y + partials ----
__global__ __launch_bounds__(256) void k_conv(float* __restrict__ ws,
                                              const float* __restrict__ cw,
                                              const float* __restrict__ cbp) {
    int b = blockIdx.y;
    int g = blockIdx.x * 256 + threadIdx.x;
    float v1 = 0.f, v2 = 0.f;
    if (g < GPB) {
        float W[6][6];
        build_w(cw, W);
        const float cb = cbp[0];
        int h = g / 65, wg = g % 65, w0 = wg * 4;
        const float* sb = ws + OFF_SPAD + b * SPIMG + h * SSTR + w0;
        float acc[4] = {cb, cb, cb, cb};
#pragma unroll
        for (int u = 0; u < 6; ++u) {
            const vfloat4* rp = reinterpret_cast<const vfloat4*>(sb + u * SSTR);
            vfloat4 A = rp[0], Bv = rp[1], Cv = rp[2];
            float r[12] = {A.x, A.y, A.z, A.w, Bv.x, Bv.y, Bv.z, Bv.w,
                           Cv.x, Cv.y, Cv.z, Cv.w};
#pragma unroll
            for (int j = 0; j < 4; ++j)
#pragma unroll
                for (int v = 0; v < 6; ++v)
                    acc[j] += W[u][v] * r[1 + j + v];
        }
        vfloat4 yo = {acc[0], acc[1], acc[2], acc[3]};
        reinterpret_cast<vfloat4*>(ws + OFF_Y + b * YIMG + h * YSTR + w0)[0] = yo;
        int nv = (wg == 64) ? 1 : 4;
#pragma unroll
        for (int j = 0; j < 4; ++j)
            if (j < nv) { v1 += acc[j]; v2 += acc[j] * acc[j]; }
    }
    // block reduce (sum, sumsq)
    for (int off = 32; off > 0; off >>= 1) {
        v1 += __shfl_down(v1, off);
        v2 += __shfl_down(v2, off);
    }
    __shared__ float red[8];
    int lane = threadIdx.x & 63, wid = threadIdx.x >> 6;
    if (lane == 0) { red[wid] = v1; red[4 + wid] = v2; }
    __syncthreads();
    if (threadIdx.x == 0) {
        int pb = b * CBLK + blockIdx.x;
        ws[OFF_PART + 2 * pb]     = red[0] + red[1] + red[2] + red[3];
        ws[OFF_PART + 2 * pb + 1] = red[4] + red[5] + red[6] + red[7];
    }
}

// ---- K4: per-block stats reduce + normalize + leaky-relu ----
__global__ __launch_bounds__(256) void k_final(const float* __restrict__ ws,
                                               float* __restrict__ out) {
    int b = blockIdx.y;
    int tid = threadIdx.x;
    float v1 = 0.f, v2 = 0.f;
    if (tid < CBLK) {
        v1 = ws[OFF_PART + 2 * (b * CBLK + tid)];
        v2 = ws[OFF_PART + 2 * (b * CBLK + tid) + 1];
    }
    for (int off = 32; off > 0; off >>= 1) {
        v1 += __shfl_down(v1, off);
        v2 += __shfl_down(v2, off);
    }
    __shared__ float red[8];
    __shared__ float st[2];
    int lane = tid & 63, wid = tid >> 6;
    if (lane == 0) { red[wid] = v1; red[4 + wid] = v2; }
    __syncthreads();
    if (tid == 0) {
        float s1 = red[0] + red[1] + red[2] + red[3];
        float s2 = red[4] + red[5] + red[6] + red[7];
        float mu = s1 / (float)NPB;
        float var = s2 / (float)NPB - mu * mu;
        st[0] = mu;
        st[1] = 1.0f / sqrtf(var + 1e-5f);
    }
    __syncthreads();
    const float mu = st[0], rs = st[1];
    int g = blockIdx.x * 256 + tid;
    if (g < GPB) {
        int h = g / 65, wg = g % 65, w0 = wg * 4;
        vfloat4 yv = reinterpret_cast<const vfloat4*>(ws + OFF_Y + b * YIMG
                                                      + h * YSTR + w0)[0];
        float yr[4] = {yv.x, yv.y, yv.z, yv.w};
        int nv = (wg == 64) ? 1 : 4;
        float* ob = out + b * NPB + h * HP + w0;
#pragma unroll
        for (int j = 0; j < 4; ++j)
            if (j < nv) {
                float z = (yr[j] - mu) * rs;
                ob[j] = (z >= 0.f) ? z : 0.01f * z;
            }
    }
}

extern "C" void kernel_launch(void* const* d_in, const int* in_sizes, int n_in,
                              void* d_out, int out_size, void* d_ws, size_t ws_size,
                              hipStream_t stream) {
    const float* x  = (const float*)d_in[0];   // [8,64,256,256]
    const float* cw = (const float*)d_in[1];   // [1,8]
    const float* cb = (const float*)d_in[2];   // [1]
    float* out = (float*)d_out;                // [8,1,257,257]
    float* ws  = (float*)d_ws;

    k_chansum<<<CHBLKS + PADBLKS, 256, 0, stream>>>(x, ws);
    dim3 g(CBLK, BB);
    k_conv<<<g, 256, 0, stream>>>(ws, cw, cb);
    k_final<<<g, 256, 0, stream>>>(ws, out);
}

// Round 9
// 190.579 us; speedup vs baseline: 1.0444x; 1.0004x over previous
//
#include <hip/hip_runtime.h>
#include <math.h>

typedef float vfloat4 __attribute__((ext_vector_type(4)));

// Problem constants
#define BB 8
#define CC 64
#define HH 256
#define WW 256
#define HP 257                     // output spatial (H+1)
#define NPB (HP * HP)              // 66049 outputs per batch

// Padded channel-sum buffer: 262 rows (3 halo top/bottom), stride 268 floats
// (4 left-halo floats for alignment, >=3 halo + vector-load slack on right).
#define SROWS 262
#define SSTR  268
#define SPIMG (SROWS * SSTR)       // 70216 floats per image
#define SSTR4 (SSTR / 4)           // 67

// y buffer: padded row stride 260 (mult of 4) for aligned float4 access
#define YSTR 260
#define YIMG (HP * YSTR)           // 66820

// Workspace layout (floats):
#define OFF_PART 0                 // 8*66*2 = 1056 partial pairs
#define OFF_Y    2048              // 8*66820 = 534560
#define OFF_SPAD 536608            // 8*70216 = 561728 (total ~4.4 MB)

// K1 sizing: 4096 half-row blocks (8 img x 256 rows x 2 halves) + 37 pad blocks
// R6/R8 best: 16-deep x 4cg full-row = 190.65us. This round probes 8-deep x 8cg.
#define CHBLKS 4096
#define PAD_PER_IMG 1170           // 6*67 full rows + 256*3 side cols
#define NPAD (BB * PAD_PER_IMG)    // 9360
#define PADBLKS ((NPAD + 255) / 256)   // 37

// K3/K4 sizing: per batch, 257 rows x 65 w-groups of 4
#define GPB (HP * 65)              // 16705 groups per batch
#define CBLK 66                    // ceil(16705/256)

// ---- K1: channel sum (8 groups x 8 ch, LDS reduce) into padded buffer ----
__global__ __launch_bounds__(256) void k_chansum(const float* __restrict__ x,
                                                 float* __restrict__ ws) {
    int blk = blockIdx.x;
    int t = threadIdx.x;
    vfloat4* sp4 = reinterpret_cast<vfloat4*>(ws + OFF_SPAD);
    if (blk < CHBLKS) {
        int img = blk >> 9;                 // 512 half-row blocks per image
        int rh = blk & 511;
        int row = rh >> 1;
        int half = rh & 1;                  // 32 float4 cols per half
        int p = t & 31;                     // float4 col within half-row
        int cg = t >> 5;                    // channel group 0..7
        const vfloat4* xp = reinterpret_cast<const vfloat4*>(x)
                            + (size_t)img * (CC * 16384)
                            + (size_t)(cg * 8) * 16384 + row * 64 + half * 32 + p;
        vfloat4 acc = {0.f, 0.f, 0.f, 0.f};
#pragma unroll
        for (int c = 0; c < 8; ++c)
            acc += __builtin_nontemporal_load(&xp[(size_t)c * 16384]);
        __shared__ vfloat4 lds[256];
        lds[t] = acc;
        __syncthreads();
        if (t < 32) {
            vfloat4 s = lds[t];
#pragma unroll
            for (int g2 = 1; g2 < 8; ++g2) s += lds[t + g2 * 32];
            sp4[img * (SPIMG / 4) + (row + 3) * SSTR4 + 1 + half * 32 + t] = s;
        }
    } else {
        int k = (blk - CHBLKS) * 256 + t;
        if (k < NPAD) {
            int img = k / PAD_PER_IMG;
            int k2 = k % PAD_PER_IMG;
            int row, col4;
            if (k2 < 402) {                 // 3 top + 3 bottom full rows
                int rr = k2 / 67;
                row = (rr < 3) ? rr : 256 + rr;   // 0,1,2 / 259,260,261
                col4 = k2 % 67;
            } else {                        // side pads, rows 3..258
                int k3 = k2 - 402;
                row = 3 + k3 / 3;
                int m = k3 % 3;
                col4 = (m == 0) ? 0 : 64 + m;     // 0, 65, 66
            }
            vfloat4 z = {0.f, 0.f, 0.f, 0.f};
            sp4[img * (SPIMG / 4) + row * SSTR4 + col4] = z;
        }
    }
}

// ---- build combined 6x6 weights: (2x2 avg-pool) ∘ (16-tap 5x5 shift stencil) ----
__device__ __forceinline__ void build_w(const float* __restrict__ cw, float W[6][6]) {
    float T[5][5];
#pragma unroll
    for (int i = 0; i < 5; ++i)
#pragma unroll
        for (int j = 0; j < 5; ++j) T[i][j] = 0.f;
#pragma unroll
    for (int d = 0; d < 5; ++d) { T[0][d] = -cw[d]; T[4][d] = cw[4 - d]; }
    T[1][4] = -cw[5]; T[2][4] = -cw[6]; T[3][4] = -cw[7];
    T[1][0] =  cw[7]; T[2][0] =  cw[6]; T[3][0] =  cw[5];
#pragma unroll
    for (int u = 0; u < 6; ++u)
#pragma unroll
        for (int v = 0; v < 6; ++v) {
            float a = 0.f;
#pragma unroll
            for (int dr = u - 1; dr <= u; ++dr)
#pragma unroll
                for (int dc = v - 1; dc <= v; ++dc)
                    if (dr >= 0 && dr < 5 && dc >= 0 && dc < 5) a += T[dr][dc];
            W[u][v] = 0.25f * a;
        }
}

// ---- K3: 6x6 stencil, 4 outputs/thread via float4 row loads; y + partials ----
__global__ __launch_bounds__(256) void k_conv(float* __restrict__ ws,
                                              const float* __restrict__ cw,
                                              const float* __restrict__ cbp) {
    int b = blockIdx.y;
    int g = blockIdx.x * 256 + threadIdx.x;
    float v1 = 0.f, v2 = 0.f;
    if (g < GPB) {
        float W[6][6];
        build_w(cw, W);
        const float cb = cbp[0];
        int h = g / 65, wg = g % 65, w0 = wg * 4;
        const float* sb = ws + OFF_SPAD + b * SPIMG + h * SSTR + w0;
        float acc[4] = {cb, cb, cb, cb};
#pragma unroll
        for (int u = 0; u < 6; ++u) {
            const vfloat4* rp = reinterpret_cast<const vfloat4*>(sb + u * SSTR);
            vfloat4 A = rp[0], Bv = rp[1], Cv = rp[2];
            float r[12] = {A.x, A.y, A.z, A.w, Bv.x, Bv.y, Bv.z, Bv.w,
                           Cv.x, Cv.y, Cv.z, Cv.w};
#pragma unroll
            for (int j = 0; j < 4; ++j)
#pragma unroll
                for (int v = 0; v < 6; ++v)
                    acc[j] += W[u][v] * r[1 + j + v];
        }
        vfloat4 yo = {acc[0], acc[1], acc[2], acc[3]};
        reinterpret_cast<vfloat4*>(ws + OFF_Y + b * YIMG + h * YSTR + w0)[0] = yo;
        int nv = (wg == 64) ? 1 : 4;
#pragma unroll
        for (int j = 0; j < 4; ++j)
            if (j < nv) { v1 += acc[j]; v2 += acc[j] * acc[j]; }
    }
    // block reduce (sum, sumsq)
    for (int off = 32; off > 0; off >>= 1) {
        v1 += __shfl_down(v1, off);
        v2 += __shfl_down(v2, off);
    }
    __shared__ float red[8];
    int lane = threadIdx.x & 63, wid = threadIdx.x >> 6;
    if (lane == 0) { red[wid] = v1; red[4 + wid] = v2; }
    __syncthreads();
    if (threadIdx.x == 0) {
        int pb = b * CBLK + blockIdx.x;
        ws[OFF_PART + 2 * pb]     = red[0] + red[1] + red[2] + red[3];
        ws[OFF_PART + 2 * pb + 1] = red[4] + red[5] + red[6] + red[7];
    }
}

// ---- K4: per-block stats reduce + normalize + leaky-relu ----
__global__ __launch_bounds__(256) void k_final(const float* __restrict__ ws,
                                               float* __restrict__ out) {
    int b = blockIdx.y;
    int tid = threadIdx.x;
    float v1 = 0.f, v2 = 0.f;
    if (tid < CBLK) {
        v1 = ws[OFF_PART + 2 * (b * CBLK + tid)];
        v2 = ws[OFF_PART + 2 * (b * CBLK + tid) + 1];
    }
    for (int off = 32; off > 0; off >>= 1) {
        v1 += __shfl_down(v1, off);
        v2 += __shfl_down(v2, off);
    }
    __shared__ float red[8];
    __shared__ float st[2];
    int lane = tid & 63, wid = tid >> 6;
    if (lane == 0) { red[wid] = v1; red[4 + wid] = v2; }
    __syncthreads();
    if (tid == 0) {
        float s1 = red[0] + red[1] + red[2] + red[3];
        float s2 = red[4] + red[5] + red[6] + red[7];
        float mu = s1 / (float)NPB;
        float var = s2 / (float)NPB - mu * mu;
        st[0] = mu;
        st[1] = 1.0f / sqrtf(var + 1e-5f);
    }
    __syncthreads();
    const float mu = st[0], rs = st[1];
    int g = blockIdx.x * 256 + tid;
    if (g < GPB) {
        int h = g / 65, wg = g % 65, w0 = wg * 4;
        vfloat4 yv = reinterpret_cast<const vfloat4*>(ws + OFF_Y + b * YIMG
                                                      + h * YSTR + w0)[0];
        float yr[4] = {yv.x, yv.y, yv.z, yv.w};
        int nv = (wg == 64) ? 1 : 4;
        float* ob = out + b * NPB + h * HP + w0;
#pragma unroll
        for (int j = 0; j < 4; ++j)
            if (j < nv) {
                float z = (yr[j] - mu) * rs;
                ob[j] = (z >= 0.f) ? z : 0.01f * z;
            }
    }
}

extern "C" void kernel_launch(void* const* d_in, const int* in_sizes, int n_in,
                              void* d_out, int out_size, void* d_ws, size_t ws_size,
                              hipStream_t stream) {
    const float* x  = (const float*)d_in[0];   // [8,64,256,256]
    const float* cw = (const float*)d_in[1];   // [1,8]
    const float* cb = (const float*)d_in[2];   // [1]
    float* out = (float*)d_out;                // [8,1,257,257]
    float* ws  = (float*)d_ws;

    k_chansum<<<CHBLKS + PADBLKS, 256, 0, stream>>>(x, ws);
    dim3 g(CBLK, BB);
    k_conv<<<g, 256, 0, stream>>>(ws, cw, cb);
    k_final<<<g, 256, 0, stream>>>(ws, out);
}